// Round 7
// baseline (952.974 us; speedup 1.0000x reference)
//
#include <hip/hip_runtime.h>
#include <cstdint>
#include <cstddef>

typedef __attribute__((ext_vector_type(4))) float f32x4;
typedef __attribute__((ext_vector_type(8))) short s16x8;
typedef __attribute__((ext_vector_type(4))) short s16x4;

__device__ __forceinline__ short f2bf(float f){
  unsigned u; __builtin_memcpy(&u, &f, 4);
  u += 0x7fffu + ((u >> 16) & 1u);
  return (short)(u >> 16);
}

// async global->LDS, 16B per lane; LDS dest is wave-uniform base + lane*16
__device__ __forceinline__ void gll16(const void* g, void* l) {
  auto* lp = (__attribute__((address_space(3))) unsigned*)(uintptr_t)(l);
  const auto* gp = (const __attribute__((address_space(1))) unsigned*)(uintptr_t)(g);
  __builtin_amdgcn_global_load_lds(gp, lp, 16, 0, 0);
}

// 8 hw-transpose reads (4 bf16 each) + one drain; a is LDS byte addr.
__device__ __forceinline__ void ds_tr8(unsigned a, s16x4* r) {
  asm volatile(
    "ds_read_b64_tr_b16 %0, %8\n\t"
    "ds_read_b64_tr_b16 %1, %8 offset:512\n\t"
    "ds_read_b64_tr_b16 %2, %8 offset:2048\n\t"
    "ds_read_b64_tr_b16 %3, %8 offset:2560\n\t"
    "ds_read_b64_tr_b16 %4, %8 offset:4096\n\t"
    "ds_read_b64_tr_b16 %5, %8 offset:4608\n\t"
    "ds_read_b64_tr_b16 %6, %8 offset:6144\n\t"
    "ds_read_b64_tr_b16 %7, %8 offset:6656\n\t"
    "s_waitcnt lgkmcnt(0)"
    : "=&v"(r[0]), "=&v"(r[1]), "=&v"(r[2]), "=&v"(r[3]),
      "=&v"(r[4]), "=&v"(r[5]), "=&v"(r[6]), "=&v"(r[7])
    : "v"(a)
    : "memory");
}

// ---------------- encode: x[N,8] @ W[8,512] + b -> fp32 resid ----------------
__global__ __launch_bounds__(256) void encode_kernel(
    const float* __restrict__ x, const float* __restrict__ W,
    const float* __restrict__ b, float* __restrict__ out)
{
  const int t = blockIdx.x;
  float xv[8];
#pragma unroll
  for (int f = 0; f < 8; ++f) xv[f] = x[(size_t)t*8 + f];
  for (int d = threadIdx.x; d < 512; d += 256) {
    float acc = b[d];
#pragma unroll
    for (int f = 0; f < 8; ++f) acc += xv[f] * W[f*512 + d];
    out[(size_t)t*512 + d] = acc;
  }
}

// ---------------- LayerNorm (no affine): fp32 in -> bf16 out ----------------
__global__ __launch_bounds__(256) void ln_kernel(
    const float* __restrict__ x, short* __restrict__ out)
{
  const int w = threadIdx.x >> 6, lane = threadIdx.x & 63;
  const int t = blockIdx.x * 4 + w;
  const float* row = x + (size_t)t * 512;
  float4 v0 = *(const float4*)&row[lane*8];
  float4 v1 = *(const float4*)&row[lane*8 + 4];
  float vals[8] = {v0.x,v0.y,v0.z,v0.w,v1.x,v1.y,v1.z,v1.w};
  float s = 0.f, sq = 0.f;
#pragma unroll
  for (int i = 0; i < 8; ++i) { s += vals[i]; sq += vals[i]*vals[i]; }
#pragma unroll
  for (int m = 1; m < 64; m <<= 1) { s += __shfl_xor(s, m); sq += __shfl_xor(sq, m); }
  float mean = s * (1.f/512.f);
  float var  = sq * (1.f/512.f) - mean*mean;
  float rstd = rsqrtf(var + 1e-5f);
  s16x8 o;
#pragma unroll
  for (int i = 0; i < 8; ++i) o[i] = f2bf((vals[i]-mean)*rstd);
  *(s16x8*)&out[(size_t)t*512 + lane*8] = o;
}

// ---------------- transpose + fp32->bf16: in[K,N] -> out[N,K] ----------------
__global__ __launch_bounds__(256) void transpose_bf16_kernel(
    const float* __restrict__ in, short* __restrict__ out, int K, int N, int kshift)
{
  const int o = blockIdx.x * 256 + threadIdx.x; // o = n*K + k
  const int k = o & (K - 1), n = o >> kshift;
  out[o] = f2bf(in[(size_t)k * N + n]);
}

__global__ __launch_bounds__(256) void convert_bf16_kernel(
    const float* __restrict__ in, short* __restrict__ out)
{
  const int i = blockIdx.x * 256 + threadIdx.x;
  out[i] = f2bf(in[i]);
}

// ---------------- GEMM: C[M,N] = A[M,K](bf16) @ Bt[N,K]^T (bf16) ----------------
// 256x256 tile, BK=32, 8 waves (2Mx4N, wave tile 128x64), mfma 16x16x32.
// T3/T4: 4 LDS buffers, prefetch depth 3, counted vmcnt (8 steady / 4,0 tail),
// one raw s_barrier per K-step. T5: COMPUTE split into 4 phases of
// {2 ds_read -> setprio(1) -> 8 MFMA -> setprio(0)} so the 2 waves/SIMD take
// different roles (one in LDS, one in MFMA) instead of lockstep bursts.
template<bool BIAS, bool RELU, bool RESID, bool OUT32>
__global__ __launch_bounds__(512, 1) void gemm_kernel(
    const short* __restrict__ A, const short* __restrict__ Bt,
    void* Cout, const float* __restrict__ bias,
    const float* resid, int M, int N, int K)
{
  __shared__ short As[4][256 * 32];   // 64 KB
  __shared__ short Bs[4][256 * 32];   // 64 KB
  const int tid = threadIdx.x;
  const int lane = tid & 63, w = tid >> 6;
  const int wr = w >> 2, wc = w & 3;
  const int q = lane & 15, g = lane >> 4;

  // T1: XCD-chunked swizzle (total blocks always a multiple of 8 here)
  const int nx = gridDim.x;
  const int d = blockIdx.y * nx + blockIdx.x;
  const int per = (nx * gridDim.y) >> 3;
  const int lid = (d & 7) * per + (d >> 3);
  const int bx = lid % nx, by = lid / nx;
  const int m0 = by * 256, n0 = bx * 256;

  // staging: chunk = 16 rows x 32 cols (1024B); wave w stages chunks 2w,2w+1
  // per operand. Source slot pre-swizzled: logical = (lane&3)^((lane>>4)&3).
  const int srow = lane >> 2;
  const int scol = (((lane & 3) ^ ((lane >> 4) & 3)) * 8);
  const short* aS0 = A  + (size_t)(m0 + w*32 + srow) * K + scol;
  const short* aS1 = aS0 + (size_t)16 * K;
  const short* bS0 = Bt + (size_t)(n0 + w*32 + srow) * K + scol;
  const short* bS1 = bS0 + (size_t)16 * K;
  const int d0 = (w*2) * 512, d1 = (w*2 + 1) * 512;

  // fragment read: logical k-group g at physical slot g^((q>>2)&3)
  const int gs = (g ^ (q >> 2)) * 8;

  f32x4 acc[8][4] = {};
  const int nt = K >> 5;    // always >= 16 here

  auto STAGE = [&](int tt) {
    const int k0 = tt << 5;
    const int nb = tt & 3;
    gll16(aS0 + k0, &As[nb][d0]);
    gll16(aS1 + k0, &As[nb][d1]);
    gll16(bS0 + k0, &Bs[nb][d0]);
    gll16(bS1 + k0, &Bs[nb][d1]);
  };
  auto COMPUTE = [&](int t) {
    const int bufc = t & 3;
    const short* Ab = &As[bufc][0];
    const short* Bb = &Bs[bufc][0];
    if (t + 3 < nt) STAGE(t + 3);
    s16x8 bF[4];
#pragma unroll
    for (int i = 0; i < 4; ++i) bF[i] = *(const s16x8*)&Bb[(wc*64 + i*16 + q)*32 + gs];
#pragma unroll
    for (int ph = 0; ph < 4; ++ph) {
      s16x8 a0 = *(const s16x8*)&Ab[(wr*128 + (2*ph    )*16 + q)*32 + gs];
      s16x8 a1 = *(const s16x8*)&Ab[(wr*128 + (2*ph + 1)*16 + q)*32 + gs];
      __builtin_amdgcn_s_setprio(1);
#pragma unroll
      for (int ni = 0; ni < 4; ++ni)
        acc[2*ph][ni] = __builtin_amdgcn_mfma_f32_16x16x32_bf16(a0, bF[ni], acc[2*ph][ni], 0, 0, 0);
#pragma unroll
      for (int ni = 0; ni < 4; ++ni)
        acc[2*ph+1][ni] = __builtin_amdgcn_mfma_f32_16x16x32_bf16(a1, bF[ni], acc[2*ph+1][ni], 0, 0, 0);
      __builtin_amdgcn_s_setprio(0);
      __builtin_amdgcn_sched_barrier(0);
    }
  };

  // prologue: stage tiles 0,1,2 (12 loads/thread in flight)
  STAGE(0); STAGE(1); STAGE(2);

  for (int t = 0; t < nt - 2; ++t) {
    // outstanding = batches t,t+1,t+2 (12). vmcnt(8): oldest-first -> batch t done.
    asm volatile("s_waitcnt vmcnt(8)" ::: "memory");
    __builtin_amdgcn_s_barrier();
    __builtin_amdgcn_sched_barrier(0);
    COMPUTE(t);
  }
  asm volatile("s_waitcnt vmcnt(4)" ::: "memory");
  __builtin_amdgcn_s_barrier();
  __builtin_amdgcn_sched_barrier(0);
  COMPUTE(nt - 2);
  asm volatile("s_waitcnt vmcnt(0)" ::: "memory");
  __builtin_amdgcn_s_barrier();
  __builtin_amdgcn_sched_barrier(0);
  COMPUTE(nt - 1);

#pragma unroll
  for (int mi = 0; mi < 8; ++mi) {
#pragma unroll
    for (int r = 0; r < 4; ++r) {
      const int gr = m0 + wr*128 + mi*16 + g*4 + r;
#pragma unroll
      for (int ni = 0; ni < 4; ++ni) {
        const int gc = n0 + wc*64 + ni*16 + q;
        float v = acc[mi][ni][r];
        if (BIAS) v += bias[gc];
        if (RELU) v = fmaxf(v, 0.f);
        if (RESID) v += resid[(size_t)gr * N + gc];
        if (OUT32) ((float*)Cout)[(size_t)gr * N + gc] = v;
        else       ((short*)Cout)[(size_t)gr * N + gc] = f2bf(v);
      }
    }
  }
}

// ---------------- flash attention ----------------
// Block = 4 waves sharing one (b,h), 64 q-rows. K/V double-buffered in LDS;
// next tile staged under current tile's softmax+PV. Swapped QK^T keeps
// softmax lane-local in q; V^T fragments via batched ds_read_b64_tr_b16.
// setprio(1) around MFMA clusters (independent blocks give role diversity).
__global__ __launch_bounds__(256) void attn_kernel(
    const short* __restrict__ qkv, short* __restrict__ attn_out)
{
  __shared__ short Ks[2][64 * 64];         // [key][64 d], slots XOR-swizzled
  __shared__ short Vs[2][64 * 64];         // [db][key][16 d] subtiles
  const int tid = threadIdx.x;
  const int w = tid >> 6, lane = tid & 63;
  const int q16 = lane & 15, g = lane >> 4;
  // T1: XCD-chunked swizzle so all (qt,h) blocks of one b stay on one XCD
  const int dd = blockIdx.x;
  const int lid = (dd & 7) * (int)(gridDim.x >> 3) + (dd >> 3);
  const int qt4 = lid & 7, h = (lid >> 3) & 7, b = lid >> 6;
  const size_t base = (size_t)b * 512 * 1536;
  const int qrow = qt4*64 + w*16 + q16;

  s16x8 bQ0, bQ1;
  {
    const size_t p = base + (size_t)qrow * 1536 + h*64 + g*8;
    bQ0 = *(const s16x8*)&qkv[p];
    bQ1 = *(const s16x8*)&qkv[p + 32];
  }

  // staging sources: wave w stages chunks 2w, 2w+1 for both K and V
  const int c0 = w*2, c1 = w*2 + 1;
  const short* kS0 = qkv + base + (size_t)(c0*8 + (lane>>3))*1536 + 512 + h*64 + ((lane&7)^(lane>>3))*8;
  const short* kS1 = qkv + base + (size_t)(c1*8 + (lane>>3))*1536 + 512 + h*64 + ((lane&7)^(lane>>3))*8;
  const short* vS0 = qkv + base + (size_t)((c0&1)*32 + (lane>>1))*1536 + 1024 + h*64 + (c0>>1)*16 + (lane&1)*8;
  const short* vS1 = qkv + base + (size_t)((c1&1)*32 + (lane>>1))*1536 + 1024 + h*64 + (c1>>1)*16 + (lane&1)*8;

  const unsigned vs_lane = (unsigned)(size_t)(&Vs[0][0]) + (unsigned)((q16 + g*64)*2);
  const int sw = q16 & 7;

  float mrun = -1e30f, ssum = 0.f;
  f32x4 O[4] = {};

  // prologue: stage tile 0 into buffer 0
  gll16(kS0, &Ks[0][c0*512]);
  gll16(kS1, &Ks[0][c1*512]);
  gll16(vS0, &Vs[0][c0*512]);
  gll16(vS1, &Vs[0][c1*512]);
  __syncthreads();

  int cur = 0;
  for (int j0 = 0; j0 < 512; j0 += 64) {
    // K fragment reads from current buffer
    s16x8 ka0[4], ka1[4];
#pragma unroll
    for (int grp = 0; grp < 4; ++grp) {
      const int rb = (grp*16 + q16) * 64;
      ka0[grp] = *(const s16x8*)&Ks[cur][rb + ((g    ) ^ sw)*8];
      ka1[grp] = *(const s16x8*)&Ks[cur][rb + ((g + 4) ^ sw)*8];
    }
    // stage next tile under this tile's compute
    if (j0 + 64 < 512) {
      const size_t joff = (size_t)(j0 + 64) * 1536;
      const int nxt = cur ^ 1;
      gll16(kS0 + joff, &Ks[nxt][c0*512]);
      gll16(kS1 + joff, &Ks[nxt][c1*512]);
      gll16(vS0 + joff, &Vs[nxt][c0*512]);
      gll16(vS1 + joff, &Vs[nxt][c1*512]);
    }
    __builtin_amdgcn_sched_barrier(0);

    // QK^T (swapped): c[grp] holds S^T[key = grp*16 + g*4 + r][q = q16]
    f32x4 c[4];
    __builtin_amdgcn_s_setprio(1);
#pragma unroll
    for (int grp = 0; grp < 4; ++grp) {
      f32x4 z = {};
      c[grp] = __builtin_amdgcn_mfma_f32_16x16x32_bf16(ka0[grp], bQ0, z, 0, 0, 0);
      c[grp] = __builtin_amdgcn_mfma_f32_16x16x32_bf16(ka1[grp], bQ1, c[grp], 0, 0, 0);
    }
    __builtin_amdgcn_s_setprio(0);

    float sc[16];
#pragma unroll
    for (int grp = 0; grp < 4; ++grp)
#pragma unroll
      for (int r = 0; r < 4; ++r) sc[grp*4 + r] = c[grp][r] * 0.125f;
    float bm = sc[0];
#pragma unroll
    for (int i = 1; i < 16; ++i) bm = fmaxf(bm, sc[i]);
    bm = fmaxf(bm, __shfl_xor(bm, 16));
    bm = fmaxf(bm, __shfl_xor(bm, 32));
    const float mn = fmaxf(mrun, bm);
    const float alpha = __expf(mrun - mn);
    float p[16]; float bs = 0.f;
#pragma unroll
    for (int i = 0; i < 16; ++i) { p[i] = __expf(sc[i] - mn); bs += p[i]; }
    bs += __shfl_xor(bs, 16);
    bs += __shfl_xor(bs, 32);
    ssum = ssum * alpha + bs;
    mrun = mn;
#pragma unroll
    for (int db = 0; db < 4; ++db) O[db] *= alpha;

    // PV: O^T[d][q] += V^T frags (batched tr-reads) x P frags (in-register)
#pragma unroll
    for (int kk = 0; kk < 2; ++kk) {
      s16x8 pf;
#pragma unroll
      for (int e = 0; e < 8; ++e) pf[e] = f2bf(p[(kk*2 + (e >> 2))*4 + (e & 3)]);
      s16x4 r[8];
      ds_tr8(vs_lane + (unsigned)(cur << 13) + (unsigned)(kk*1024), r);
      __builtin_amdgcn_sched_barrier(0);
      __builtin_amdgcn_s_setprio(1);
#pragma unroll
      for (int db = 0; db < 4; ++db) {
        s16x8 vf = __builtin_shufflevector(r[2*db], r[2*db + 1], 0, 1, 2, 3, 4, 5, 6, 7);
        O[db] = __builtin_amdgcn_mfma_f32_16x16x32_bf16(vf, pf, O[db], 0, 0, 0);
      }
      __builtin_amdgcn_s_setprio(0);
    }
    __syncthreads();
    cur ^= 1;
  }

  const float inv = 1.f / ssum;
  const size_t tok = (size_t)b*512 + qrow;
#pragma unroll
  for (int db = 0; db < 4; ++db) {
    s16x4 ov;
#pragma unroll
    for (int r = 0; r < 4; ++r) ov[r] = f2bf(O[db][r] * inv);
    *(s16x4*)&attn_out[tok*512 + h*64 + db*16 + g*4] = ov;
  }
}

// ---------------- finalize: resid -> d_out(seq) fp32 + bf16 copy ----------------
__global__ __launch_bounds__(256) void finalize_seq_kernel(
    const float* __restrict__ resid, float* __restrict__ outseq, short* __restrict__ obf)
{
  const size_t i = (size_t)blockIdx.x * 256 + threadIdx.x;
  const float v = resid[i];
  outseq[i] = v;
  obf[i] = f2bf(v);
}

// ---------------- cn2[k] = ||centers_k||^2 ----------------
__global__ __launch_bounds__(256) void cn2_kernel(
    const float* __restrict__ centers, float* __restrict__ cn2)
{
  const int c = blockIdx.x;
  __shared__ float red[256];
  float s = 0.f;
  for (int d = threadIdx.x; d < 512; d += 256) { float v = centers[(size_t)c*512 + d]; s += v*v; }
  red[threadIdx.x] = s; __syncthreads();
  for (int off = 128; off > 0; off >>= 1) {
    if (threadIdx.x < off) red[threadIdx.x] += red[threadIdx.x + off];
    __syncthreads();
  }
  if (threadIdx.x == 0) cn2[c] = red[0];
}

// ---------------- argmin over centers + fp32 ||diff||^2 partial sums ----------------
__global__ __launch_bounds__(256) void argmin_kernel(
    const float* __restrict__ gdist, const float* __restrict__ cn2,
    const float* __restrict__ resid, const float* __restrict__ centers,
    float* __restrict__ partial)
{
  const int w = threadIdx.x >> 6, lane = threadIdx.x & 63;
  const int t = blockIdx.x * 4 + w;
  float best = 1e30f; int bi = 0;
#pragma unroll
  for (int j = 0; j < 8; ++j) {
    const int k = j*64 + lane;
    const float v = cn2[k] - 2.f * gdist[(size_t)t*512 + k];
    if (v < best || (v == best && k < bi)) { best = v; bi = k; }
  }
#pragma unroll
  for (int mm = 1; mm < 64; mm <<= 1) {
    const float ov = __shfl_xor(best, mm); const int oi = __shfl_xor(bi, mm);
    if (ov < best || (ov == best && oi < bi)) { best = ov; bi = oi; }
  }
  float s = 0.f;
#pragma unroll
  for (int j = 0; j < 2; ++j) {
    float4 o = *(const float4*)&resid[(size_t)t*512 + lane*8 + j*4];
    float4 c = *(const float4*)&centers[(size_t)bi*512 + lane*8 + j*4];
    const float dx = o.x-c.x, dy = o.y-c.y, dz = o.z-c.z, dw = o.w-c.w;
    s += dx*dx + dy*dy + dz*dz + dw*dw;
  }
#pragma unroll
  for (int mm = 1; mm < 64; mm <<= 1) s += __shfl_xor(s, mm);
  __shared__ float red[4];
  if (lane == 0) red[w] = s;
  __syncthreads();
  if (threadIdx.x == 0) partial[blockIdx.x] = red[0] + red[1] + red[2] + red[3];
}

__global__ __launch_bounds__(256) void loss_kernel(
    const float* __restrict__ partial, int n, float* __restrict__ out)
{
  float s = 0.f;
  for (int i = threadIdx.x; i < n; i += 256) s += partial[i];
  __shared__ float red[256];
  red[threadIdx.x] = s; __syncthreads();
  for (int off = 128; off > 0; off >>= 1) {
    if (threadIdx.x < off) red[threadIdx.x] += red[threadIdx.x + off];
    __syncthreads();
  }
  if (threadIdx.x == 0) out[0] = red[0] * (1.f / 32768.f);
}

// ==========================================================================
extern "C" void kernel_launch(void* const* d_in, const int* in_sizes, int n_in,
                              void* d_out, int out_size, void* d_ws, size_t ws_size,
                              hipStream_t stream) {
  const float* x     = (const float*)d_in[0];
  const float* enc_W = (const float*)d_in[1];
  const float* enc_b = (const float*)d_in[2];
  const float* Wqkv  = (const float*)d_in[3];
  const float* Wo    = (const float*)d_in[4];
  const float* W1    = (const float*)d_in[5];
  const float* b1    = (const float*)d_in[6];
  const float* W2    = (const float*)d_in[7];
  const float* b2    = (const float*)d_in[8];
  const float* cen   = (const float*)d_in[9];
  float* out = (float*)d_out;

  const int NT = 32768;           // B*S tokens
  char* ws = (char*)d_ws;
  float* resid   = (float*)(ws);                                  // 64 MB
  short* h_ln    = (short*)(ws + 67108864);                       // 32 MB (also o_bf16)
  char*  pool    = ws + 100663296;                                // 128 MB shared pool
  short* qkv     = (short*)pool;                                  // 96 MB
  short* attn_o  = (short*)(pool + 100663296);                    // 32 MB (after qkv)
  short* hidden  = (short*)pool;                                  // 128 MB (after attn done)
  float* gdist   = (float*)pool;                                  // 64 MB (after hidden done)
  short* wbase   = (short*)(ws + 234881024);                      // ~12.5 MB bf16 weights
  short* wqT     = wbase;                                         // 2 x 1536*512
  short* woT     = wbase + 1572864;                                // 2 x 512*512
  short* w1T     = wbase + 2097152;                                // 2 x 2048*512
  short* w2T     = wbase + 4194304;                                // 2 x 512*2048
  short* cenb    = wbase + 6291456;                                // 512*512
  float* cn2     = (float*)(ws + 247988224);
  float* partial = (float*)(ws + 247990272);

  // ---- weight prep (transpose to [N,K] + bf16) ----
  for (int l = 0; l < 2; ++l) {
    transpose_bf16_kernel<<<3072, 256, 0, stream>>>(Wqkv + (size_t)l*512*1536, wqT + (size_t)l*786432, 512, 1536, 9);
    transpose_bf16_kernel<<<1024, 256, 0, stream>>>(Wo   + (size_t)l*512*512,  woT + (size_t)l*262144, 512, 512, 9);
    transpose_bf16_kernel<<<4096, 256, 0, stream>>>(W1   + (size_t)l*512*2048, w1T + (size_t)l*1048576, 512, 2048, 9);
    transpose_bf16_kernel<<<4096, 256, 0, stream>>>(W2   + (size_t)l*2048*512, w2T + (size_t)l*1048576, 2048, 512, 11);
  }
  convert_bf16_kernel<<<1024, 256, 0, stream>>>(cen, cenb);
  cn2_kernel<<<512, 256, 0, stream>>>(cen, cn2);

  // ---- encode ----
  encode_kernel<<<NT, 256, 0, stream>>>(x, enc_W, enc_b, resid);

  // ---- layers ----
  for (int l = 0; l < 2; ++l) {
    ln_kernel<<<NT/4, 256, 0, stream>>>(resid, h_ln);
    gemm_kernel<false,false,false,false><<<dim3(6, 128), 512, 0, stream>>>(
        h_ln, wqT + (size_t)l*786432, qkv, nullptr, nullptr, NT, 1536, 512);
    attn_kernel<<<4096, 256, 0, stream>>>(qkv, attn_o);
    gemm_kernel<false,false,true,true><<<dim3(2, 128), 512, 0, stream>>>(
        attn_o, woT + (size_t)l*262144, resid, nullptr, resid, NT, 512, 512);
    ln_kernel<<<NT/4, 256, 0, stream>>>(resid, h_ln);
    gemm_kernel<true,true,false,false><<<dim3(8, 128), 512, 0, stream>>>(
        h_ln, w1T + (size_t)l*1048576, hidden, b1 + (size_t)l*2048, nullptr, NT, 2048, 512);
    gemm_kernel<true,false,true,true><<<dim3(2, 128), 512, 0, stream>>>(
        hidden, w2T + (size_t)l*1048576, resid, b2 + (size_t)l*512, resid, NT, 512, 2048);
  }

  // ---- head: output_seq + cdist/argmin/loss ----
  finalize_seq_kernel<<<65536, 256, 0, stream>>>(resid, out + 1, h_ln);
  gemm_kernel<false,false,false,true><<<dim3(2, 128), 512, 0, stream>>>(
      h_ln, cenb, gdist, nullptr, nullptr, NT, 512, 512);
  argmin_kernel<<<NT/4, 256, 0, stream>>>(gdist, cn2, resid, cen, partial);
  loss_kernel<<<1, 256, 0, stream>>>(partial, NT/4, out);
}

// Round 8
// 947.802 us; speedup vs baseline: 1.0055x; 1.0055x over previous
//
#include <hip/hip_runtime.h>
#include <cstdint>
#include <cstddef>

typedef __attribute__((ext_vector_type(4))) float f32x4;
typedef __attribute__((ext_vector_type(8))) short s16x8;
typedef __attribute__((ext_vector_type(4))) short s16x4;

__device__ __forceinline__ short f2bf(float f){
  unsigned u; __builtin_memcpy(&u, &f, 4);
  u += 0x7fffu + ((u >> 16) & 1u);
  return (short)(u >> 16);
}

// async global->LDS, 16B per lane; LDS dest is wave-uniform base + lane*16
__device__ __forceinline__ void gll16(const void* g, void* l) {
  auto* lp = (__attribute__((address_space(3))) unsigned*)(uintptr_t)(l);
  const auto* gp = (const __attribute__((address_space(1))) unsigned*)(uintptr_t)(g);
  __builtin_amdgcn_global_load_lds(gp, lp, 16, 0, 0);
}

// 8 hw-transpose reads (4 bf16 each) + one drain; a is LDS byte addr.
__device__ __forceinline__ void ds_tr8(unsigned a, s16x4* r) {
  asm volatile(
    "ds_read_b64_tr_b16 %0, %8\n\t"
    "ds_read_b64_tr_b16 %1, %8 offset:512\n\t"
    "ds_read_b64_tr_b16 %2, %8 offset:2048\n\t"
    "ds_read_b64_tr_b16 %3, %8 offset:2560\n\t"
    "ds_read_b64_tr_b16 %4, %8 offset:4096\n\t"
    "ds_read_b64_tr_b16 %5, %8 offset:4608\n\t"
    "ds_read_b64_tr_b16 %6, %8 offset:6144\n\t"
    "ds_read_b64_tr_b16 %7, %8 offset:6656\n\t"
    "s_waitcnt lgkmcnt(0)"
    : "=&v"(r[0]), "=&v"(r[1]), "=&v"(r[2]), "=&v"(r[3]),
      "=&v"(r[4]), "=&v"(r[5]), "=&v"(r[6]), "=&v"(r[7])
    : "v"(a)
    : "memory");
}

// ---------------- encode: x[N,8] @ W[8,512] + b -> fp32 resid ----------------
__global__ __launch_bounds__(256) void encode_kernel(
    const float* __restrict__ x, const float* __restrict__ W,
    const float* __restrict__ b, float* __restrict__ out)
{
  const int t = blockIdx.x;
  float xv[8];
#pragma unroll
  for (int f = 0; f < 8; ++f) xv[f] = x[(size_t)t*8 + f];
  for (int d = threadIdx.x; d < 512; d += 256) {
    float acc = b[d];
#pragma unroll
    for (int f = 0; f < 8; ++f) acc += xv[f] * W[f*512 + d];
    out[(size_t)t*512 + d] = acc;
  }
}

// ---------------- LayerNorm (no affine): fp32 in -> bf16 out ----------------
__global__ __launch_bounds__(256) void ln_kernel(
    const float* __restrict__ x, short* __restrict__ out)
{
  const int w = threadIdx.x >> 6, lane = threadIdx.x & 63;
  const int t = blockIdx.x * 4 + w;
  const float* row = x + (size_t)t * 512;
  float4 v0 = *(const float4*)&row[lane*8];
  float4 v1 = *(const float4*)&row[lane*8 + 4];
  float vals[8] = {v0.x,v0.y,v0.z,v0.w,v1.x,v1.y,v1.z,v1.w};
  float s = 0.f, sq = 0.f;
#pragma unroll
  for (int i = 0; i < 8; ++i) { s += vals[i]; sq += vals[i]*vals[i]; }
#pragma unroll
  for (int m = 1; m < 64; m <<= 1) { s += __shfl_xor(s, m); sq += __shfl_xor(sq, m); }
  float mean = s * (1.f/512.f);
  float var  = sq * (1.f/512.f) - mean*mean;
  float rstd = rsqrtf(var + 1e-5f);
  s16x8 o;
#pragma unroll
  for (int i = 0; i < 8; ++i) o[i] = f2bf((vals[i]-mean)*rstd);
  *(s16x8*)&out[(size_t)t*512 + lane*8] = o;
}

// ---------------- transpose + fp32->bf16: in[K,N] -> out[N,K] ----------------
__global__ __launch_bounds__(256) void transpose_bf16_kernel(
    const float* __restrict__ in, short* __restrict__ out, int K, int N, int kshift)
{
  const int o = blockIdx.x * 256 + threadIdx.x; // o = n*K + k
  const int k = o & (K - 1), n = o >> kshift;
  out[o] = f2bf(in[(size_t)k * N + n]);
}

__global__ __launch_bounds__(256) void convert_bf16_kernel(
    const float* __restrict__ in, short* __restrict__ out)
{
  const int i = blockIdx.x * 256 + threadIdx.x;
  out[i] = f2bf(in[i]);
}

// ---------------- GEMM: C[M,N] = A[M,K](bf16) @ Bt[N,K]^T (bf16) ----------------
// 256x256 tile, BK=32, 8 waves (2Mx4N, wave tile 128x64), mfma 16x16x32.
// m201-style phased schedule: per K-tile, 2 phases of
//   {counted vmcnt + barrier | ds_read frag subtile + stage half of tile t+2
//    -> sched_barrier -> setprio(1) 16 MFMA setprio(0) -> s_barrier}
// vmcnt is COUNTED (4) in the main loop, never 0 (loads stay in flight across
// barriers); depth-2 tile lookahead over 4 LDS buffers; last iter peeled w/ vmcnt(0).
template<bool BIAS, bool RELU, bool RESID, bool OUT32>
__global__ __launch_bounds__(512, 1) void gemm_kernel(
    const short* __restrict__ A, const short* __restrict__ Bt,
    void* Cout, const float* __restrict__ bias,
    const float* resid, int M, int N, int K)
{
  __shared__ short As[4][256 * 32];   // 64 KB
  __shared__ short Bs[4][256 * 32];   // 64 KB
  const int tid = threadIdx.x;
  const int lane = tid & 63, w = tid >> 6;
  const int wr = w >> 2, wc = w & 3;
  const int q = lane & 15, g = lane >> 4;

  // T1: XCD-chunked swizzle (total blocks always a multiple of 8 here)
  const int nx = gridDim.x;
  const int d = blockIdx.y * nx + blockIdx.x;
  const int per = (nx * gridDim.y) >> 3;
  const int lid = (d & 7) * per + (d >> 3);
  const int bx = lid % nx, by = lid / nx;
  const int m0 = by * 256, n0 = bx * 256;

  // staging: chunk = 16 rows x 32 cols (1024B); wave w stages chunks 2w,2w+1
  // per operand. Source slot pre-swizzled: logical = (lane&3)^((lane>>4)&3).
  const int srow = lane >> 2;
  const int scol = (((lane & 3) ^ ((lane >> 4) & 3)) * 8);
  const short* aS0 = A  + (size_t)(m0 + w*32 + srow) * K + scol;
  const short* aS1 = aS0 + (size_t)16 * K;
  const short* bS0 = Bt + (size_t)(n0 + w*32 + srow) * K + scol;
  const short* bS1 = bS0 + (size_t)16 * K;
  const int d0 = (w*2) * 512, d1 = (w*2 + 1) * 512;

  // fragment read: logical k-group g at physical slot g^((q>>2)&3)
  const int gs = (g ^ (q >> 2)) * 8;

  f32x4 acc[8][4] = {};
  const int nt = K >> 5;    // always >= 16 here

  auto STAGE_A = [&](int tt) {
    const int k0 = tt << 5, nb = tt & 3;
    gll16(aS0 + k0, &As[nb][d0]);
    gll16(aS1 + k0, &As[nb][d1]);
  };
  auto STAGE_B = [&](int tt) {
    const int k0 = tt << 5, nb = tt & 3;
    gll16(bS0 + k0, &Bs[nb][d0]);
    gll16(bS1 + k0, &Bs[nb][d1]);
  };

  // one K-tile body: 2 phases. PRE = stage tile t+2 (split A/B across phases).
  auto TILE = [&](int t, bool pre) {
    const int bufc = t & 3;
    const short* Ab = &As[bufc][0];
    const short* Bb = &Bs[bufc][0];
    // ---- phase 0: B frags + A frags mi0..3, stage A(t+2), MFMA quads 0..3
    s16x8 bF[4], aF[4];
#pragma unroll
    for (int i = 0; i < 4; ++i) bF[i] = *(const s16x8*)&Bb[(wc*64 + i*16 + q)*32 + gs];
#pragma unroll
    for (int i = 0; i < 4; ++i) aF[i] = *(const s16x8*)&Ab[(wr*128 + i*16 + q)*32 + gs];
    if (pre) STAGE_A(t + 2);
    __builtin_amdgcn_sched_barrier(0);
    __builtin_amdgcn_s_setprio(1);
#pragma unroll
    for (int mi = 0; mi < 4; ++mi)
#pragma unroll
      for (int ni = 0; ni < 4; ++ni)
        acc[mi][ni] = __builtin_amdgcn_mfma_f32_16x16x32_bf16(aF[mi], bF[ni], acc[mi][ni], 0, 0, 0);
    __builtin_amdgcn_s_setprio(0);
    __builtin_amdgcn_s_barrier();
    // ---- phase 1: A frags mi4..7, stage B(t+2), MFMA quads 4..7
    s16x8 aG[4];
#pragma unroll
    for (int i = 0; i < 4; ++i) aG[i] = *(const s16x8*)&Ab[(wr*128 + (4+i)*16 + q)*32 + gs];
    if (pre) STAGE_B(t + 2);
    __builtin_amdgcn_sched_barrier(0);
    __builtin_amdgcn_s_setprio(1);
#pragma unroll
    for (int mi = 0; mi < 4; ++mi)
#pragma unroll
      for (int ni = 0; ni < 4; ++ni)
        acc[4+mi][ni] = __builtin_amdgcn_mfma_f32_16x16x32_bf16(aG[mi], bF[ni], acc[4+mi][ni], 0, 0, 0);
    __builtin_amdgcn_s_setprio(0);
    __builtin_amdgcn_s_barrier();
  };

  // prologue: stage tiles 0,1 (8 loads/thread in flight; tile 0 oldest)
  STAGE_A(0); STAGE_B(0); STAGE_A(1); STAGE_B(1);

  for (int t = 0; t < nt - 1; ++t) {
    // outstanding: {A,B}(t), {A,B}(t+1) [+ t+2 partially after phase 0].
    // vmcnt(4): oldest 4 (= tile t) retired -> tile t fully in LDS.
    asm volatile("s_waitcnt vmcnt(4)" ::: "memory");
    __builtin_amdgcn_s_barrier();
    TILE(t, t + 2 < nt);
  }
  asm volatile("s_waitcnt vmcnt(0)" ::: "memory");
  __builtin_amdgcn_s_barrier();
  TILE(nt - 1, false);

#pragma unroll
  for (int mi = 0; mi < 8; ++mi) {
#pragma unroll
    for (int r = 0; r < 4; ++r) {
      const int gr = m0 + wr*128 + mi*16 + g*4 + r;
#pragma unroll
      for (int ni = 0; ni < 4; ++ni) {
        const int gc = n0 + wc*64 + ni*16 + q;
        float v = acc[mi][ni][r];
        if (BIAS) v += bias[gc];
        if (RELU) v = fmaxf(v, 0.f);
        if (RESID) v += resid[(size_t)gr * N + gc];
        if (OUT32) ((float*)Cout)[(size_t)gr * N + gc] = v;
        else       ((short*)Cout)[(size_t)gr * N + gc] = f2bf(v);
      }
    }
  }
}

// ---------------- flash attention ----------------
// Block = 4 waves sharing one (b,h), 64 q-rows. K/V double-buffered in LDS;
// next tile staged under current tile's softmax+PV. Swapped QK^T keeps
// softmax lane-local in q; V^T fragments via batched ds_read_b64_tr_b16.
__global__ __launch_bounds__(256) void attn_kernel(
    const short* __restrict__ qkv, short* __restrict__ attn_out)
{
  __shared__ short Ks[2][64 * 64];         // [key][64 d], slots XOR-swizzled
  __shared__ short Vs[2][64 * 64];         // [db][key][16 d] subtiles
  const int tid = threadIdx.x;
  const int w = tid >> 6, lane = tid & 63;
  const int q16 = lane & 15, g = lane >> 4;
  // T1: XCD-chunked swizzle so all (qt,h) blocks of one b stay on one XCD
  const int dd = blockIdx.x;
  const int lid = (dd & 7) * (int)(gridDim.x >> 3) + (dd >> 3);
  const int qt4 = lid & 7, h = (lid >> 3) & 7, b = lid >> 6;
  const size_t base = (size_t)b * 512 * 1536;
  const int qrow = qt4*64 + w*16 + q16;

  s16x8 bQ0, bQ1;
  {
    const size_t p = base + (size_t)qrow * 1536 + h*64 + g*8;
    bQ0 = *(const s16x8*)&qkv[p];
    bQ1 = *(const s16x8*)&qkv[p + 32];
  }

  // staging sources: wave w stages chunks 2w, 2w+1 for both K and V
  const int c0 = w*2, c1 = w*2 + 1;
  const short* kS0 = qkv + base + (size_t)(c0*8 + (lane>>3))*1536 + 512 + h*64 + ((lane&7)^(lane>>3))*8;
  const short* kS1 = qkv + base + (size_t)(c1*8 + (lane>>3))*1536 + 512 + h*64 + ((lane&7)^(lane>>3))*8;
  const short* vS0 = qkv + base + (size_t)((c0&1)*32 + (lane>>1))*1536 + 1024 + h*64 + (c0>>1)*16 + (lane&1)*8;
  const short* vS1 = qkv + base + (size_t)((c1&1)*32 + (lane>>1))*1536 + 1024 + h*64 + (c1>>1)*16 + (lane&1)*8;

  const unsigned vs_lane = (unsigned)(size_t)(&Vs[0][0]) + (unsigned)((q16 + g*64)*2);
  const int sw = q16 & 7;

  float mrun = -1e30f, ssum = 0.f;
  f32x4 O[4] = {};

  // prologue: stage tile 0 into buffer 0
  gll16(kS0, &Ks[0][c0*512]);
  gll16(kS1, &Ks[0][c1*512]);
  gll16(vS0, &Vs[0][c0*512]);
  gll16(vS1, &Vs[0][c1*512]);
  __syncthreads();

  int cur = 0;
  for (int j0 = 0; j0 < 512; j0 += 64) {
    // K fragment reads from current buffer
    s16x8 ka0[4], ka1[4];
#pragma unroll
    for (int grp = 0; grp < 4; ++grp) {
      const int rb = (grp*16 + q16) * 64;
      ka0[grp] = *(const s16x8*)&Ks[cur][rb + ((g    ) ^ sw)*8];
      ka1[grp] = *(const s16x8*)&Ks[cur][rb + ((g + 4) ^ sw)*8];
    }
    // stage next tile under this tile's compute
    if (j0 + 64 < 512) {
      const size_t joff = (size_t)(j0 + 64) * 1536;
      const int nxt = cur ^ 1;
      gll16(kS0 + joff, &Ks[nxt][c0*512]);
      gll16(kS1 + joff, &Ks[nxt][c1*512]);
      gll16(vS0 + joff, &Vs[nxt][c0*512]);
      gll16(vS1 + joff, &Vs[nxt][c1*512]);
    }
    __builtin_amdgcn_sched_barrier(0);

    // QK^T (swapped): c[grp] holds S^T[key = grp*16 + g*4 + r][q = q16]
    f32x4 c[4];
    __builtin_amdgcn_s_setprio(1);
#pragma unroll
    for (int grp = 0; grp < 4; ++grp) {
      f32x4 z = {};
      c[grp] = __builtin_amdgcn_mfma_f32_16x16x32_bf16(ka0[grp], bQ0, z, 0, 0, 0);
      c[grp] = __builtin_amdgcn_mfma_f32_16x16x32_bf16(ka1[grp], bQ1, c[grp], 0, 0, 0);
    }
    __builtin_amdgcn_s_setprio(0);

    float sc[16];
#pragma unroll
    for (int grp = 0; grp < 4; ++grp)
#pragma unroll
      for (int r = 0; r < 4; ++r) sc[grp*4 + r] = c[grp][r] * 0.125f;
    float bm = sc[0];
#pragma unroll
    for (int i = 1; i < 16; ++i) bm = fmaxf(bm, sc[i]);
    bm = fmaxf(bm, __shfl_xor(bm, 16));
    bm = fmaxf(bm, __shfl_xor(bm, 32));
    const float mn = fmaxf(mrun, bm);
    const float alpha = __expf(mrun - mn);
    float p[16]; float bs = 0.f;
#pragma unroll
    for (int i = 0; i < 16; ++i) { p[i] = __expf(sc[i] - mn); bs += p[i]; }
    bs += __shfl_xor(bs, 16);
    bs += __shfl_xor(bs, 32);
    ssum = ssum * alpha + bs;
    mrun = mn;
#pragma unroll
    for (int db = 0; db < 4; ++db) O[db] *= alpha;

    // PV: O^T[d][q] += V^T frags (batched tr-reads) x P frags (in-register)
#pragma unroll
    for (int kk = 0; kk < 2; ++kk) {
      s16x8 pf;
#pragma unroll
      for (int e = 0; e < 8; ++e) pf[e] = f2bf(p[(kk*2 + (e >> 2))*4 + (e & 3)]);
      s16x4 r[8];
      ds_tr8(vs_lane + (unsigned)(cur << 13) + (unsigned)(kk*1024), r);
      __builtin_amdgcn_sched_barrier(0);
      __builtin_amdgcn_s_setprio(1);
#pragma unroll
      for (int db = 0; db < 4; ++db) {
        s16x8 vf = __builtin_shufflevector(r[2*db], r[2*db + 1], 0, 1, 2, 3, 4, 5, 6, 7);
        O[db] = __builtin_amdgcn_mfma_f32_16x16x32_bf16(vf, pf, O[db], 0, 0, 0);
      }
      __builtin_amdgcn_s_setprio(0);
    }
    __syncthreads();
    cur ^= 1;
  }

  const float inv = 1.f / ssum;
  const size_t tok = (size_t)b*512 + qrow;
#pragma unroll
  for (int db = 0; db < 4; ++db) {
    s16x4 ov;
#pragma unroll
    for (int r = 0; r < 4; ++r) ov[r] = f2bf(O[db][r] * inv);
    *(s16x4*)&attn_out[tok*512 + h*64 + db*16 + g*4] = ov;
  }
}

// ---------------- finalize: resid -> d_out(seq) fp32 + bf16 copy ----------------
__global__ __launch_bounds__(256) void finalize_seq_kernel(
    const float* __restrict__ resid, float* __restrict__ outseq, short* __restrict__ obf)
{
  const size_t i = (size_t)blockIdx.x * 256 + threadIdx.x;
  const float v = resid[i];
  outseq[i] = v;
  obf[i] = f2bf(v);
}

// ---------------- cn2[k] = ||centers_k||^2 ----------------
__global__ __launch_bounds__(256) void cn2_kernel(
    const float* __restrict__ centers, float* __restrict__ cn2)
{
  const int c = blockIdx.x;
  __shared__ float red[256];
  float s = 0.f;
  for (int d = threadIdx.x; d < 512; d += 256) { float v = centers[(size_t)c*512 + d]; s += v*v; }
  red[threadIdx.x] = s; __syncthreads();
  for (int off = 128; off > 0; off >>= 1) {
    if (threadIdx.x < off) red[threadIdx.x] += red[threadIdx.x + off];
    __syncthreads();
  }
  if (threadIdx.x == 0) cn2[c] = red[0];
}

// ---------------- argmin over centers + fp32 ||diff||^2 partial sums ----------------
__global__ __launch_bounds__(256) void argmin_kernel(
    const float* __restrict__ gdist, const float* __restrict__ cn2,
    const float* __restrict__ resid, const float* __restrict__ centers,
    float* __restrict__ partial)
{
  const int w = threadIdx.x >> 6, lane = threadIdx.x & 63;
  const int t = blockIdx.x * 4 + w;
  float best = 1e30f; int bi = 0;
#pragma unroll
  for (int j = 0; j < 8; ++j) {
    const int k = j*64 + lane;
    const float v = cn2[k] - 2.f * gdist[(size_t)t*512 + k];
    if (v < best || (v == best && k < bi)) { best = v; bi = k; }
  }
#pragma unroll
  for (int mm = 1; mm < 64; mm <<= 1) {
    const float ov = __shfl_xor(best, mm); const int oi = __shfl_xor(bi, mm);
    if (ov < best || (ov == best && oi < bi)) { best = ov; bi = oi; }
  }
  float s = 0.f;
#pragma unroll
  for (int j = 0; j < 2; ++j) {
    float4 o = *(const float4*)&resid[(size_t)t*512 + lane*8 + j*4];
    float4 c = *(const float4*)&centers[(size_t)bi*512 + lane*8 + j*4];
    const float dx = o.x-c.x, dy = o.y-c.y, dz = o.z-c.z, dw = o.w-c.w;
    s += dx*dx + dy*dy + dz*dz + dw*dw;
  }
#pragma unroll
  for (int mm = 1; mm < 64; mm <<= 1) s += __shfl_xor(s, mm);
  __shared__ float red[4];
  if (lane == 0) red[w] = s;
  __syncthreads();
  if (threadIdx.x == 0) partial[blockIdx.x] = red[0] + red[1] + red[2] + red[3];
}

__global__ __launch_bounds__(256) void loss_kernel(
    const float* __restrict__ partial, int n, float* __restrict__ out)
{
  float s = 0.f;
  for (int i = threadIdx.x; i < n; i += 256) s += partial[i];
  __shared__ float red[256];
  red[threadIdx.x] = s; __syncthreads();
  for (int off = 128; off > 0; off >>= 1) {
    if (threadIdx.x < off) red[threadIdx.x] += red[threadIdx.x + off];
    __syncthreads();
  }
  if (threadIdx.x == 0) out[0] = red[0] * (1.f / 32768.f);
}

// ==========================================================================
extern "C" void kernel_launch(void* const* d_in, const int* in_sizes, int n_in,
                              void* d_out, int out_size, void* d_ws, size_t ws_size,
                              hipStream_t stream) {
  const float* x     = (const float*)d_in[0];
  const float* enc_W = (const float*)d_in[1];
  const float* enc_b = (const float*)d_in[2];
  const float* Wqkv  = (const float*)d_in[3];
  const float* Wo    = (const float*)d_in[4];
  const float* W1    = (const float*)d_in[5];
  const float* b1    = (const float*)d_in[6];
  const float* W2    = (const float*)d_in[7];
  const float* b2    = (const float*)d_in[8];
  const float* cen   = (const float*)d_in[9];
  float* out = (float*)d_out;

  const int NT = 32768;           // B*S tokens
  char* ws = (char*)d_ws;
  float* resid   = (float*)(ws);                                  // 64 MB
  short* h_ln    = (short*)(ws + 67108864);                       // 32 MB (also o_bf16)
  char*  pool    = ws + 100663296;                                // 128 MB shared pool
  short* qkv     = (short*)pool;                                  // 96 MB
  short* attn_o  = (short*)(pool + 100663296);                    // 32 MB (after qkv)
  short* hidden  = (short*)pool;                                  // 128 MB (after attn done)
  float* gdist   = (float*)pool;                                  // 64 MB (after hidden done)
  short* wbase   = (short*)(ws + 234881024);                      // ~12.5 MB bf16 weights
  short* wqT     = wbase;                                         // 2 x 1536*512
  short* woT     = wbase + 1572864;                                // 2 x 512*512
  short* w1T     = wbase + 2097152;                                // 2 x 2048*512
  short* w2T     = wbase + 4194304;                                // 2 x 512*2048
  short* cenb    = wbase + 6291456;                                // 512*512
  float* cn2     = (float*)(ws + 247988224);
  float* partial = (float*)(ws + 247990272);

  // ---- weight prep (transpose to [N,K] + bf16) ----
  for (int l = 0; l < 2; ++l) {
    transpose_bf16_kernel<<<3072, 256, 0, stream>>>(Wqkv + (size_t)l*512*1536, wqT + (size_t)l*786432, 512, 1536, 9);
    transpose_bf16_kernel<<<1024, 256, 0, stream>>>(Wo   + (size_t)l*512*512,  woT + (size_t)l*262144, 512, 512, 9);
    transpose_bf16_kernel<<<4096, 256, 0, stream>>>(W1   + (size_t)l*512*2048, w1T + (size_t)l*1048576, 512, 2048, 9);
    transpose_bf16_kernel<<<4096, 256, 0, stream>>>(W2   + (size_t)l*2048*512, w2T + (size_t)l*1048576, 2048, 512, 11);
  }
  convert_bf16_kernel<<<1024, 256, 0, stream>>>(cen, cenb);
  cn2_kernel<<<512, 256, 0, stream>>>(cen, cn2);

  // ---- encode ----
  encode_kernel<<<NT, 256, 0, stream>>>(x, enc_W, enc_b, resid);

  // ---- layers ----
  for (int l = 0; l < 2; ++l) {
    ln_kernel<<<NT/4, 256, 0, stream>>>(resid, h_ln);
    gemm_kernel<false,false,false,false><<<dim3(6, 128), 512, 0, stream>>>(
        h_ln, wqT + (size_t)l*786432, qkv, nullptr, nullptr, NT, 1536, 512);
    attn_kernel<<<4096, 256, 0, stream>>>(qkv, attn_o);
    gemm_kernel<false,false,true,true><<<dim3(2, 128), 512, 0, stream>>>(
        attn_o, woT + (size_t)l*262144, resid, nullptr, resid, NT, 512, 512);
    ln_kernel<<<NT/4, 256, 0, stream>>>(resid, h_ln);
    gemm_kernel<true,true,false,false><<<dim3(8, 128), 512, 0, stream>>>(
        h_ln, w1T + (size_t)l*1048576, hidden, b1 + (size_t)l*2048, nullptr, NT, 2048, 512);
    gemm_kernel<true,false,true,true><<<dim3(2, 128), 512, 0, stream>>>(
        hidden, w2T + (size_t)l*1048576, resid, b2 + (size_t)l*512, resid, NT, 512, 2048);
  }

  // ---- head: output_seq + cdist/argmin/loss ----
  finalize_seq_kernel<<<65536, 256, 0, stream>>>(resid, out + 1, h_ln);
  gemm_kernel<false,false,false,true><<<dim3(2, 128), 512, 0, stream>>>(
      h_ln, cenb, gdist, nullptr, nullptr, NT, 512, 512);
  argmin_kernel<<<NT/4, 256, 0, stream>>>(gdist, cn2, resid, cen, partial);
  loss_kernel<<<1, 256, 0, stream>>>(partial, NT/4, out);
}